// Round 2
// baseline (1235.822 us; speedup 1.0000x reference)
//
#include <hip/hip_runtime.h>
#include <hip/hip_bf16.h>

#define AS1 __attribute__((address_space(1)))
#define AS3 __attribute__((address_space(3)))

typedef __attribute__((ext_vector_type(4))) float  f32x4;
typedef __attribute__((ext_vector_type(8))) __bf16 bf16x8;
typedef __attribute__((ext_vector_type(2))) __bf16 bf16x2;
typedef __attribute__((ext_vector_type(4))) unsigned int uint4_;

static __device__ __forceinline__ unsigned short f2bf_rne(float f) {
    unsigned int u = __builtin_bit_cast(unsigned int, f);
    u += 0x7fffu + ((u >> 16) & 1u);
    return (unsigned short)(u >> 16);
}

static __device__ __forceinline__ unsigned int pack2(float a, float b) {
#if __has_builtin(__builtin_amdgcn_cvt_pk_bf16_f32)
    bf16x2 r = __builtin_amdgcn_cvt_pk_bf16_f32(a, b);
    return __builtin_bit_cast(unsigned int, r);
#else
    return (unsigned int)f2bf_rne(a) | ((unsigned int)f2bf_rne(b) << 16);
#endif
}

// ---------------------------------------------------------------------------
// K0a: convert w_e = attn_w[:, 1024:3072] (1024 x 2048) fp32 -> bf16 bits
// ---------------------------------------------------------------------------
__global__ __launch_bounds__(256) void convwe_kernel(
    const float* __restrict__ attn_w, unsigned short* __restrict__ Bw)
{
    const int idx = (blockIdx.x * 256 + threadIdx.x) * 8;  // < 1024*2048
    const int h = idx >> 11;
    const int e = idx & 2047;
    const float* src = attn_w + h * 3072 + 1024 + e;
    f32x4 v0 = *(const f32x4*)src;
    f32x4 v1 = *(const f32x4*)(src + 4);
    uint4_ o;
    o.x = pack2(v0.x, v0.y); o.y = pack2(v0.z, v0.w);
    o.z = pack2(v1.x, v1.y); o.w = pack2(v1.z, v1.w);
    *(uint4_*)(Bw + idx) = o;
}

// ---------------------------------------------------------------------------
// K0b: hid_proj[b,h] = sum_k hidden[b,k] * attn_w[h,k] + attn_b[h]   (fp32)
// ---------------------------------------------------------------------------
__global__ __launch_bounds__(256) void hidproj_kernel(
    const float* __restrict__ hidden, const float* __restrict__ attn_w,
    const float* __restrict__ attn_b, float* __restrict__ hp)
{
    __shared__ float wrow[1024];
    const int h = blockIdx.x;
    const int t = threadIdx.x;
#pragma unroll
    for (int i = 0; i < 4; ++i) wrow[t + i * 256] = attn_w[h * 3072 + t + i * 256];
    __syncthreads();
    const int wave = t >> 6, lane = t & 63;
    const float bias = attn_b[h];
    for (int b = wave; b < 32; b += 4) {
        float s = 0.f;
#pragma unroll
        for (int j = 0; j < 16; ++j)
            s = fmaf(hidden[b * 1024 + lane + j * 64], wrow[lane + j * 64], s);
#pragma unroll
        for (int off = 1; off < 64; off <<= 1) s += __shfl_xor(s, off);
        if (lane == 0) hp[b * 1024 + h] = s + bias;
    }
}

// ---------------------------------------------------------------------------
// K1: fused-convert 256x256-tile 8-phase bf16 MFMA GEMM
//     (M=65536, N=1024, K=2048), A = enc fp32 read directly.
//
//   - 512 threads = 8 waves (2M x 4N); per-wave C = 128x64 (8x4 16x16 frags)
//   - BK=64/tile, 2-slot double buffer per operand (2 x 32 KiB each = 128 KiB)
//   - slot(row,k8) = row*8 + (k8 ^ (row&7)); 16-lane read groups hit all 8
//     bank-groups (2-way = free). A written via per-lane ds_write_b128
//     (swizzle direct); B via global_load_lds with inverse-swizzled source.
//   - A staged through regs (T14): P3 of tile kt converts A(kt+1) (loaded at
//     P3 of kt-1, ~4 phases of HBM-latency cover) and issues A(kt+2) loads.
//     Compiler inserts the precise vmcnt(4) before the converts (it counts
//     the 4 intervening B gload_lds); main loop branch-free so counts exact.
//   - manual waits only at tile end: vmcnt(8) (drain B, keep 8 A-loads in
//     flight across the barrier) + lgkmcnt(0) (publish ds_writes).
//   - T5 setprio around MFMA clusters; XCD-swizzled blockIdx (1024 %8==0).
// Epilogue: scores[m] += sum_n vw[n]*tanh(hp[b,n]+C[m,n]) partials (atomic).
// ---------------------------------------------------------------------------
__global__ __launch_bounds__(512, 2) void gemm8f_score_kernel(
    const float* __restrict__ enc,           // 65536 x 2048 fp32 (A source)
    const unsigned short* __restrict__ Bw,   // 1024 x 2048 bf16 bits
    const float* __restrict__ hp,            // 32 x 1024 fp32
    const float* __restrict__ vw,            // 1024 fp32
    float* __restrict__ scores)              // 65536 fp32 (pre-zeroed)
{
    __shared__ unsigned short lds[65536];    // A: [0,32768) 2 bufs; B: [32768,65536)

    const int bid = blockIdx.x;
    const int swz = (bid & 7) * 128 + (bid >> 3);   // bijective, 1024%8==0
    const int mt  = swz >> 2;                       // 0..255
    const int nt  = swz & 3;                        // 0..3
    const long tile_m = (long)mt * 256;
    const int  tile_n = nt * 256;

    const int tid  = threadIdx.x;
    const int w    = tid >> 6;
    const int lane = tid & 63;
    const int quad = lane >> 4;
    const int l15  = lane & 15;
    const int wm   = w >> 2;   // 0..1
    const int wn   = w & 3;    // 0..3

    // ---- A reg-staging: thread owns row=tid>>1, 32 contiguous k-floats ----
    const int arow = tid >> 1;              // 0..255
    const int ah4  = (tid & 1) * 4;         // k8 base (4h)
    const int ar7  = arow & 7;
    const float* ap = enc + (size_t)(tile_m + arow) * 2048 + (tid & 1) * 32;
    const int awb  = arow * 64;             // slot*8 base (ushort units)
    const int awo0 = awb + ((ah4 + 0) ^ ar7) * 8;
    const int awo1 = awb + ((ah4 + 1) ^ ar7) * 8;
    const int awo2 = awb + ((ah4 + 2) ^ ar7) * 8;
    const int awo3 = awb + ((ah4 + 3) ^ ar7) * 8;

    // ---- B gload_lds staging: inst j covers rows (w*4+j)*8 + (lane>>3) ----
    const int brl = lane >> 3;
    const int bk8 = (lane & 7) ^ brl;       // inverse-swizzled source k8
    const unsigned short* bp = Bw + (size_t)(tile_n + w * 32 + brl) * 2048 + bk8 * 8;

    // ---- reader constants ----
    const int l7  = l15 & 7;
    const int arb = (wm * 128 + l15) * 64;
    const int brb = (wn * 64 + l15) * 64;
    const int sw0 = ((quad)     ^ l7) * 8;  // kk0
    const int sw1 = ((quad + 4) ^ l7) * 8;  // kk1

    f32x4 acc[8][4];
#pragma unroll
    for (int i = 0; i < 8; ++i)
#pragma unroll
        for (int j = 0; j < 4; ++j) acc[i][j] = (f32x4){0.f, 0.f, 0.f, 0.f};

    f32x4 av0, av1, av2, av3, av4, av5, av6, av7;
    bf16x8 af[4], bfr[4];
    int ak = 0, kb = 0;

#define G2L(srcp, dsti) __builtin_amdgcn_global_load_lds((const AS1 void*)(srcp), (AS3 void*)(&lds[(dsti)]), 16, 0, 0)
#define PRIO1 __builtin_amdgcn_s_setprio(1)
#define PRIO0 __builtin_amdgcn_s_setprio(0)
#define BARX() do { asm volatile("" ::: "memory"); __builtin_amdgcn_s_barrier(); asm volatile("" ::: "memory"); } while (0)

#define ISSB(NXT) do {                                              \
    const unsigned short* bs_ = bp + kb;                            \
    const int bd_ = 32768 + (NXT) * 16384 + w * 2048;               \
    G2L(bs_,          bd_);                                         \
    G2L(bs_ + 16384,  bd_ + 512);                                   \
    G2L(bs_ + 32768,  bd_ + 1024);                                  \
    G2L(bs_ + 49152,  bd_ + 1536);                                  \
} while (0)

#define LOADA() do {                                                \
    const float* as_ = ap + ak;                                     \
    av0 = *(const f32x4*)(as_);      av1 = *(const f32x4*)(as_ + 4);  \
    av2 = *(const f32x4*)(as_ + 8);  av3 = *(const f32x4*)(as_ + 12); \
    av4 = *(const f32x4*)(as_ + 16); av5 = *(const f32x4*)(as_ + 20); \
    av6 = *(const f32x4*)(as_ + 24); av7 = *(const f32x4*)(as_ + 28); \
} while (0)

#define CONVA(NXT) do {                                             \
    const int ab_ = (NXT) * 16384;                                  \
    uint4_ q_;                                                      \
    q_.x = pack2(av0.x, av0.y); q_.y = pack2(av0.z, av0.w);         \
    q_.z = pack2(av1.x, av1.y); q_.w = pack2(av1.z, av1.w);         \
    *(uint4_*)&lds[ab_ + awo0] = q_;                                \
    q_.x = pack2(av2.x, av2.y); q_.y = pack2(av2.z, av2.w);         \
    q_.z = pack2(av3.x, av3.y); q_.w = pack2(av3.z, av3.w);         \
    *(uint4_*)&lds[ab_ + awo1] = q_;                                \
    q_.x = pack2(av4.x, av4.y); q_.y = pack2(av4.z, av4.w);         \
    q_.z = pack2(av5.x, av5.y); q_.w = pack2(av5.z, av5.w);         \
    *(uint4_*)&lds[ab_ + awo2] = q_;                                \
    q_.x = pack2(av6.x, av6.y); q_.y = pack2(av6.z, av6.w);         \
    q_.z = pack2(av7.x, av7.y); q_.w = pack2(av7.z, av7.w);         \
    *(uint4_*)&lds[ab_ + awo3] = q_;                                \
} while (0)

#define RDA(CUR, MB, SW) do {                                       \
    const int aa_ = (CUR) * 16384 + arb + (SW);                     \
    af[0] = *(const bf16x8*)&lds[aa_ + ((MB) + 0) * 1024];          \
    af[1] = *(const bf16x8*)&lds[aa_ + ((MB) + 1) * 1024];          \
    af[2] = *(const bf16x8*)&lds[aa_ + ((MB) + 2) * 1024];          \
    af[3] = *(const bf16x8*)&lds[aa_ + ((MB) + 3) * 1024];          \
} while (0)

#define RDB(CUR, SW) do {                                           \
    const int bb_ = 32768 + (CUR) * 16384 + brb + (SW);             \
    bfr[0] = *(const bf16x8*)&lds[bb_];                             \
    bfr[1] = *(const bf16x8*)&lds[bb_ + 1024];                      \
    bfr[2] = *(const bf16x8*)&lds[bb_ + 2048];                      \
    bfr[3] = *(const bf16x8*)&lds[bb_ + 3072];                      \
} while (0)

#define MFMA_BLK(MB) do {                                           \
    _Pragma("unroll")                                               \
    for (int mi = 0; mi < 4; ++mi)                                  \
    _Pragma("unroll")                                               \
        for (int ni = 0; ni < 4; ++ni)                              \
            acc[(MB) + mi][ni] = __builtin_amdgcn_mfma_f32_16x16x32_bf16( \
                af[mi], bfr[ni], acc[(MB) + mi][ni], 0, 0, 0);      \
} while (0)

#define TILE(CUR, NXT, DO_B, DO_CONV, DO_NA, EW, DO_END) do {       \
    /* P0 */                                                        \
    if (DO_B) { ISSB(NXT); kb += 64; }                              \
    RDA(CUR, 0, sw0); RDB(CUR, sw0);                                \
    BARX(); PRIO1; MFMA_BLK(0); PRIO0; BARX();                      \
    /* P1 */                                                        \
    RDA(CUR, 4, sw0);                                               \
    BARX(); PRIO1; MFMA_BLK(4); PRIO0; BARX();                      \
    /* P2 */                                                        \
    RDA(CUR, 0, sw1); RDB(CUR, sw1);                                \
    BARX(); PRIO1; MFMA_BLK(0); PRIO0; BARX();                      \
    /* P3 */                                                        \
    RDA(CUR, 4, sw1);                                               \
    if (DO_CONV) CONVA(NXT);                                        \
    if (DO_NA) { LOADA(); ak += 64; }                               \
    BARX(); PRIO1; MFMA_BLK(4); PRIO0;                              \
    if (DO_END) {                                                   \
        asm volatile("s_waitcnt " EW " lgkmcnt(0)" ::: "memory");   \
        BARX();                                                     \
    }                                                               \
} while (0)

    // ---- prologue: A(0)->regs->Abuf0, B(0)->Bbuf0, A(1)->regs ----
    LOADA(); ak += 64;        // A(0)
    ISSB(0); kb += 64;        // B(0)
    CONVA(0);                 // compiler waits vmcnt(4): A(0) regs ready
    LOADA(); ak += 64;        // A(1)
    asm volatile("s_waitcnt vmcnt(8) lgkmcnt(0)" ::: "memory");  // B(0) landed
    BARX();

    // ---- main loop: tiles 0..29 branch-free ----
    for (int kt = 0; kt < 30; kt += 2) {
        TILE(0, 1, 1, 1, 1, "vmcnt(8)", 1);
        TILE(1, 0, 1, 1, 1, "vmcnt(8)", 1);
    }
    // tile 30: stage B(31)+convert A(31), no new A loads, drain fully
    TILE(0, 1, 1, 1, 0, "vmcnt(0)", 1);
    // tile 31: pure compute
    TILE(1, 0, 0, 0, 0, "", 0);

#undef G2L
#undef PRIO1
#undef PRIO0
#undef BARX
#undef ISSB
#undef LOADA
#undef CONVA
#undef RDA
#undef RDB
#undef MFMA_BLK
#undef TILE

    // ---- epilogue: score partials ----
    const int bidx = (int)(tile_m >> 11);
    float vwv[4], hpv[4];
#pragma unroll
    for (int ni = 0; ni < 4; ++ni) {
        const int n = tile_n + wn * 64 + ni * 16 + l15;
        vwv[ni] = vw[n];
        hpv[ni] = hp[bidx * 1024 + n];
    }
#pragma unroll
    for (int mi = 0; mi < 8; ++mi) {
#pragma unroll
        for (int r = 0; r < 4; ++r) {
            float s = 0.f;
#pragma unroll
            for (int ni = 0; ni < 4; ++ni) {
                float x = hpv[ni] + acc[mi][ni][r];
                x = fminf(fmaxf(x, -12.f), 12.f);
                const float e  = __expf(x + x);
                const float th = (e - 1.f) * __builtin_amdgcn_rcpf(e + 1.f);
                s = fmaf(vwv[ni], th, s);
            }
            s += __shfl_xor(s, 1);
            s += __shfl_xor(s, 2);
            s += __shfl_xor(s, 4);
            s += __shfl_xor(s, 8);
            if (l15 == 0)
                atomicAdd(&scores[tile_m + wm * 128 + mi * 16 + quad * 4 + r], s);
        }
    }
}

// ---------------------------------------------------------------------------
// K2: softmax over S=2048, one block per batch
// ---------------------------------------------------------------------------
__global__ __launch_bounds__(256) void softmax_kernel(float* __restrict__ sc)
{
    __shared__ float red[8];
    const int b = blockIdx.x, t = threadIdx.x;
    const int wave = t >> 6, lane = t & 63;
    float* p = sc + b * 2048;
    float v[8];
#pragma unroll
    for (int i = 0; i < 8; ++i) v[i] = p[t + i * 256];
    float m = v[0];
#pragma unroll
    for (int i = 1; i < 8; ++i) m = fmaxf(m, v[i]);
#pragma unroll
    for (int off = 1; off < 64; off <<= 1) m = fmaxf(m, __shfl_xor(m, off));
    if (lane == 0) red[wave] = m;
    __syncthreads();
    m = fmaxf(fmaxf(red[0], red[1]), fmaxf(red[2], red[3]));
    float s = 0.f;
#pragma unroll
    for (int i = 0; i < 8; ++i) { v[i] = __expf(v[i] - m); s += v[i]; }
#pragma unroll
    for (int off = 1; off < 64; off <<= 1) s += __shfl_xor(s, off);
    if (lane == 0) red[4 + wave] = s;
    __syncthreads();
    s = red[4] + red[5] + red[6] + red[7];
    const float inv = 1.0f / s;
#pragma unroll
    for (int i = 0; i < 8; ++i) p[t + i * 256] = v[i] * inv;
}

// ---------------------------------------------------------------------------
// K3: context partials — block (b, sc) owns 64 s-rows (1024 blocks = 4/CU)
// ---------------------------------------------------------------------------
__global__ __launch_bounds__(256) void context_part_kernel(
    const float* __restrict__ enc, const float* __restrict__ attn,
    float* __restrict__ part)
{
    const int b  = blockIdx.x >> 5;   // 32 batches
    const int sc = blockIdx.x & 31;   // 32 chunks of 64 rows
    const int t  = threadIdx.x;
    const float* ep = enc + ((size_t)(b * 2048 + sc * 64)) * 2048 + t * 8;
    const float* ap = attn + b * 2048 + sc * 64;
    f32x4 a0 = (f32x4){0.f, 0.f, 0.f, 0.f};
    f32x4 a1 = (f32x4){0.f, 0.f, 0.f, 0.f};
#pragma unroll 4
    for (int s = 0; s < 64; ++s) {
        const float w = ap[s];
        f32x4 v0 = *(const f32x4*)ep;
        f32x4 v1 = *(const f32x4*)(ep + 4);
        a0 += w * v0;
        a1 += w * v1;
        ep += 2048;
    }
    float* pp = part + ((size_t)(b * 32 + sc)) * 2048 + t * 8;
    *(f32x4*)pp = a0;
    *(f32x4*)(pp + 4) = a1;
}

__global__ __launch_bounds__(256) void context_reduce_kernel(
    const float* __restrict__ part, float* __restrict__ ctx)
{
    const int idx = blockIdx.x * 256 + threadIdx.x;  // 65536 = b*2048 + e
    const int b = idx >> 11, e = idx & 2047;
    const float* pp = part + ((size_t)b * 32) * 2048 + e;
    float s = 0.f;
#pragma unroll
    for (int i = 0; i < 32; ++i) s += pp[i * 2048];
    ctx[idx] = s;
}

// ---------------------------------------------------------------------------
// K3-fallback: atomic context (used only if ws can't hold partials)
// ---------------------------------------------------------------------------
__global__ __launch_bounds__(256) void context_kernel(
    const float* __restrict__ enc, const float* __restrict__ attn,
    float* __restrict__ ctx)
{
    const int b  = blockIdx.x >> 5;
    const int sc = blockIdx.x & 31;
    const int t  = threadIdx.x;
    const float* ep = enc + ((long)(b * 2048 + sc * 64)) * 2048 + t * 8;
    const float* ap = attn + b * 2048 + sc * 64;
    f32x4 a0 = (f32x4){0.f, 0.f, 0.f, 0.f};
    f32x4 a1 = (f32x4){0.f, 0.f, 0.f, 0.f};
#pragma unroll 4
    for (int s = 0; s < 64; ++s) {
        const float w = ap[s];
        f32x4 v0 = *(const f32x4*)ep;
        f32x4 v1 = *(const f32x4*)(ep + 4);
        a0 += w * v0;
        a1 += w * v1;
        ep += 2048;
    }
    float* cp = ctx + b * 2048 + t * 8;
    atomicAdd(&cp[0], a0.x); atomicAdd(&cp[1], a0.y);
    atomicAdd(&cp[2], a0.z); atomicAdd(&cp[3], a0.w);
    atomicAdd(&cp[4], a1.x); atomicAdd(&cp[5], a1.y);
    atomicAdd(&cp[6], a1.z); atomicAdd(&cp[7], a1.w);
}

// ---------------------------------------------------------------------------
extern "C" void kernel_launch(void* const* d_in, const int* in_sizes, int n_in,
                              void* d_out, int out_size, void* d_ws, size_t ws_size,
                              hipStream_t stream)
{
    const float* hidden = (const float*)d_in[0];   // 32 x 1024
    const float* enc    = (const float*)d_in[1];   // 32 x 2048 x 2048
    const float* attn_w = (const float*)d_in[2];   // 1024 x 3072
    const float* attn_b = (const float*)d_in[3];   // 1024
    const float* vw     = (const float*)d_in[4];   // 1024
    float* out = (float*)d_out;

    // ws layout: [Bw 4MiB][hp 128KiB][part 8MiB]
    const size_t off_Bw   = 0;
    const size_t off_hp   = (size_t)1024 * 2048 * 2;            // 4 MiB
    const size_t off_part = off_hp + (size_t)32 * 1024 * 4;     // +128 KiB
    const size_t need_part = off_part + (size_t)1024 * 2048 * 4;// +8 MiB

    unsigned short* Bw   = (unsigned short*)((char*)d_ws + off_Bw);
    float*          hp   = (float*)((char*)d_ws + off_hp);
    float*          part = (float*)((char*)d_ws + off_part);

    float* ctx  = out;            // 32 x 2048
    float* attn = out + 65536;    // 32 x 2048 (scores -> weights in place)

    hipMemsetAsync(d_out, 0, (size_t)out_size * 4, stream);
    convwe_kernel <<<1024, 256, 0, stream>>>(attn_w, Bw);
    hidproj_kernel<<<1024, 256, 0, stream>>>(hidden, attn_w, attn_b, hp);

    gemm8f_score_kernel<<<1024, 512, 0, stream>>>(enc, Bw, hp, vw, attn);

    softmax_kernel<<<32, 256, 0, stream>>>(attn);

    if (ws_size >= need_part) {
        context_part_kernel  <<<1024, 256, 0, stream>>>(enc, attn, part);
        context_reduce_kernel<<<256, 256, 0, stream>>>(part, ctx);
    } else {
        context_kernel<<<1024, 256, 0, stream>>>(enc, attn, ctx);
    }
}